// Round 2
// baseline (892.299 us; speedup 1.0000x reference)
//
#include <hip/hip_runtime.h>

typedef __attribute__((ext_vector_type(8))) short short8;
typedef __attribute__((ext_vector_type(4))) float f32x4;
typedef unsigned short u16;
typedef unsigned int u32;

#define MFMA16(a, b, c) __builtin_amdgcn_mfma_f32_16x16x32_bf16((a), (b), (c), 0, 0, 0)
#define SCALE_Q 0.1767766952966369f

__device__ __forceinline__ u16 f2bf(float x) {
  u32 u = __float_as_uint(x);
  u32 r = u + 0x7FFF + ((u >> 16) & 1);
  return (u16)(r >> 16);
}

__device__ __forceinline__ float gelu_f(float x) {
  float u = 0.7978845608f * (x + 0.044715f * x * x * x);
  float e = __expf(2.f * u);
  float t = 1.f - 2.f / (e + 1.f);
  return 0.5f * x * (1.f + t);
}

// ---------------- K0a: weight transpose + bf16 cast ----------------
__global__ __launch_bounds__(256) void k0_weights(
    const float* __restrict__ wq, const float* __restrict__ wk, const float* __restrict__ wv,
    const float* __restrict__ wo, const float* __restrict__ w1, const float* __restrict__ w2,
    const float* __restrict__ bq, const float* __restrict__ bk, const float* __restrict__ bv,
    u16* __restrict__ wqkvt, u16* __restrict__ wot, u16* __restrict__ w1t, u16* __restrict__ w2t,
    float* __restrict__ bqkv) {
  int idx = blockIdx.x * 256 + threadIdx.x;
  if (idx < 49152) {                       // wqkvt[384][128] = W^T, q cols pre-scaled
    int n = idx >> 7, k = idx & 127;
    float v;
    if (n < 128) v = wq[k * 128 + n] * SCALE_Q;
    else if (n < 256) v = wk[k * 128 + (n - 128)];
    else v = wv[k * 128 + (n - 256)];
    wqkvt[idx] = f2bf(v);
  } else if (idx < 65536) {                // wot[128][128]
    int j = idx - 49152;
    int n = j >> 7, k = j & 127;
    wot[j] = f2bf(wo[k * 128 + n]);
  } else if (idx < 131072) {               // w1t[512][128]
    int j = idx - 65536;
    int n = j >> 7, k = j & 127;
    w1t[j] = f2bf(w1[k * 512 + n]);
  } else if (idx < 196608) {               // w2t[128][512]
    int j = idx - 131072;
    int n = j >> 9, k = j & 511;
    w2t[j] = f2bf(w2[k * 128 + n]);
  } else if (idx < 196992) {               // bqkv[384]
    int n = idx - 196608;
    float v;
    if (n < 128) v = bq[n] * SCALE_Q;
    else if (n < 256) v = bk[n - 128];
    else v = bv[n - 256];
    bqkv[n] = v;
  }
}

// ---------------- K0b: bias+mask table in MFMA C-fragment layout ----------------
// layout: [wi 64][h 4][mt 4][nt 4][lane 64][reg 4] f32
__global__ __launch_bounds__(256) void k0_biasmask(const float* __restrict__ rel, float* __restrict__ bm) {
  int idx = blockIdx.x * 256 + threadIdx.x;   // 0 .. 1048575
  int reg = idx & 3;
  int lane = (idx >> 2) & 63;
  int nt = (idx >> 8) & 3;
  int mt = (idx >> 10) & 3;
  int h = (idx >> 12) & 3;
  int wi = idx >> 14;
  int r = mt * 16 + ((lane >> 4) << 2) + reg;  // query token in window
  int c = nt * 16 + (lane & 15);               // key token
  float v = -1e30f;
  if (r < 49 && c < 49) {
    int qr = r / 7, qc = r % 7, kr = c / 7, kc = c % 7;
    int i0 = (kr - qr + 13) % 13, i1 = (kc - qc + 13) % 13;
    v = rel[(i0 * 13 + i1) * 4 + h];
    int gh = (wi >> 3) * 7 + qr, gw = (wi & 7) * 7 + qc;
    int kh = (wi >> 3) * 7 + kr, kw = (wi & 7) * 7 + kc;
    int rq = (gh < 49 ? 0 : (gh < 53 ? 1 : 2)) * 3 + (gw < 49 ? 0 : (gw < 53 ? 1 : 2));
    int rk = (kh < 49 ? 0 : (kh < 53 ? 1 : 2)) * 3 + (kw < 49 ? 0 : (kw < 53 ? 1 : 2));
    if (rq != rk) v -= 100.f;
  }
  bm[idx] = v;
}

// ---------------- K1: LN1 + roll(-3,-3) + window partition -> bf16 ----------------
__global__ __launch_bounds__(256) void k1_ln1(const float* __restrict__ x, const float* __restrict__ g,
                                              const float* __restrict__ b, u16* __restrict__ hwin) {
  int wid = threadIdx.x >> 6, lane = threadIdx.x & 63;
  int t = blockIdx.x * 4 + wid;
  float2 v = *(const float2*)(x + t * 128 + lane * 2);
  float s = v.x + v.y;
#pragma unroll
  for (int o = 1; o < 64; o <<= 1) s += __shfl_xor(s, o);
  float mu = s * 0.0078125f;
  float dx = v.x - mu, dy = v.y - mu;
  float q = dx * dx + dy * dy;
#pragma unroll
  for (int o = 1; o < 64; o <<= 1) q += __shfl_xor(q, o);
  float rstd = rsqrtf(q * 0.0078125f + 1e-5f);
  float y0 = dx * rstd * g[lane * 2] + b[lane * 2];
  float y1 = dy * rstd * g[lane * 2 + 1] + b[lane * 2 + 1];
  int bi = t / 3136, hw = t - bi * 3136;
  int oh = hw / 56, ow = hw - oh * 56;
  int gh = oh - 3; if (gh < 0) gh += 56;
  int gw = ow - 3; if (gw < 0) gw += 56;
  int win = bi * 64 + (gh / 7) * 8 + gw / 7;
  int n = (gh % 7) * 7 + (gw % 7);
  u32 packed = (u32)f2bf(y0) | ((u32)f2bf(y1) << 16);
  *(u32*)(hwin + (win * 49 + n) * 128 + lane * 2) = packed;
}

// ---------------- K2: QKV GEMM, no-LDS direct-fragment (M=200704, K=128, N=384) ----------------
__global__ __launch_bounds__(256) void k2_qkv(const u16* __restrict__ hwin, const u16* __restrict__ wt,
                                              const float* __restrict__ bqkv, u16* __restrict__ qb,
                                              u16* __restrict__ kb, u16* __restrict__ vt) {
  int tid = threadIdx.x, lane = tid & 63, w = tid >> 6;
  int g = lane >> 4, l15 = lane & 15;
  int row0 = blockIdx.x * 256 + w * 64;
  short8 a[4][4];
#pragma unroll
  for (int mt = 0; mt < 4; ++mt)
#pragma unroll
    for (int kt = 0; kt < 4; ++kt)
      a[mt][kt] = *(const short8*)(hwin + (size_t)(row0 + mt * 16 + l15) * 128 + kt * 32 + g * 8);
  const f32x4 vz = {0.f, 0.f, 0.f, 0.f};
  for (int nb = 0; nb < 6; ++nb) {
    f32x4 acc[4][4];
#pragma unroll
    for (int i = 0; i < 4; ++i)
#pragma unroll
      for (int j = 0; j < 4; ++j) acc[i][j] = vz;
#pragma unroll
    for (int kt = 0; kt < 4; ++kt) {
      short8 bfr[4];
#pragma unroll
      for (int nt = 0; nt < 4; ++nt)
        bfr[nt] = *(const short8*)(wt + (size_t)(nb * 64 + nt * 16 + l15) * 128 + kt * 32 + g * 8);
#pragma unroll
      for (int mt = 0; mt < 4; ++mt)
#pragma unroll
        for (int nt = 0; nt < 4; ++nt) acc[mt][nt] = MFMA16(a[mt][kt], bfr[nt], acc[mt][nt]);
    }
#pragma unroll
    for (int mt = 0; mt < 4; ++mt)
#pragma unroll
      for (int nt = 0; nt < 4; ++nt) {
        int ng = nb * 64 + nt * 16 + l15;
        float bias = bqkv[ng];
#pragma unroll
        for (int reg = 0; reg < 4; ++reg) {
          int token = row0 + mt * 16 + g * 4 + reg;
          u16 hv = f2bf(acc[mt][nt][reg] + bias);
          if (nb < 2) qb[(size_t)token * 128 + ng] = hv;
          else if (nb < 4) kb[(size_t)token * 128 + ng - 128] = hv;
          else {
            int c = ng - 256;
            int win = token / 49, nn = token - win * 49;
            vt[(size_t)win * 8192 + c * 64 + nn] = hv;
          }
        }
      }
  }
}

// ---------------- K3: windowed attention, one wave per (window, head) ----------------
__global__ __launch_bounds__(256) void k3_attn(const u16* __restrict__ qb, const u16* __restrict__ kb,
                                               const u16* __restrict__ vt, const float* __restrict__ bm,
                                               u16* __restrict__ ao) {
  __shared__ u16 pl[4 * 4096];
  int win = blockIdx.x;
  int lane = threadIdx.x & 63, head = threadIdx.x >> 6;
  int g = lane >> 4, l15 = lane & 15;
  u16* myp = pl + head * 4096;
  short8 aq[4], bk_[4];
#pragma unroll
  for (int mt = 0; mt < 4; ++mt)
    aq[mt] = *(const short8*)(qb + (size_t)(win * 49 + mt * 16 + l15) * 128 + head * 32 + g * 8);
#pragma unroll
  for (int nt = 0; nt < 4; ++nt)
    bk_[nt] = *(const short8*)(kb + (size_t)(win * 49 + nt * 16 + l15) * 128 + head * 32 + g * 8);
  const f32x4* bmv = (const f32x4*)bm + ((win & 63) * 4 + head) * 1024;
  f32x4 s[4][4];
#pragma unroll
  for (int mt = 0; mt < 4; ++mt)
#pragma unroll
    for (int nt = 0; nt < 4; ++nt) s[mt][nt] = bmv[(mt * 4 + nt) * 64 + lane];
#pragma unroll
  for (int mt = 0; mt < 4; ++mt)
#pragma unroll
    for (int nt = 0; nt < 4; ++nt) s[mt][nt] = MFMA16(aq[mt], bk_[nt], s[mt][nt]);
#pragma unroll
  for (int mt = 0; mt < 4; ++mt)
#pragma unroll
    for (int reg = 0; reg < 4; ++reg) {
      float m = fmaxf(fmaxf(s[mt][0][reg], s[mt][1][reg]), fmaxf(s[mt][2][reg], s[mt][3][reg]));
#pragma unroll
      for (int o = 1; o < 16; o <<= 1) m = fmaxf(m, __shfl_xor(m, o));
      float p0 = __expf(s[mt][0][reg] - m);
      float p1 = __expf(s[mt][1][reg] - m);
      float p2 = __expf(s[mt][2][reg] - m);
      float p3 = __expf(s[mt][3][reg] - m);
      float sum = p0 + p1 + p2 + p3;
#pragma unroll
      for (int o = 1; o < 16; o <<= 1) sum += __shfl_xor(sum, o);
      float rinv = 1.f / sum;
      s[mt][0][reg] = p0 * rinv; s[mt][1][reg] = p1 * rinv;
      s[mt][2][reg] = p2 * rinv; s[mt][3][reg] = p3 * rinv;
    }
#pragma unroll
  for (int mt = 0; mt < 4; ++mt)
#pragma unroll
    for (int nt = 0; nt < 4; ++nt)
#pragma unroll
      for (int reg = 0; reg < 4; ++reg) {
        int r = mt * 16 + g * 4 + reg, c = nt * 16 + l15;
        int byte_ = ((r << 7) + (c << 1)) ^ ((r & 7) << 4);
        *(u16*)((char*)myp + byte_) = f2bf(s[mt][nt][reg]);
      }
  __syncthreads();
  short8 vb[2][2];
#pragma unroll
  for (int kk = 0; kk < 2; ++kk)
#pragma unroll
    for (int n2 = 0; n2 < 2; ++n2)
      vb[kk][n2] = *(const short8*)(vt + (size_t)win * 8192 + (head * 32 + n2 * 16 + l15) * 64 + kk * 32 + g * 8);
  const f32x4 vz = {0.f, 0.f, 0.f, 0.f};
  f32x4 o[4][2];
#pragma unroll
  for (int mt = 0; mt < 4; ++mt) { o[mt][0] = vz; o[mt][1] = vz; }
#pragma unroll
  for (int mt = 0; mt < 4; ++mt)
#pragma unroll
    for (int kk = 0; kk < 2; ++kk) {
      int r = mt * 16 + l15;
      int byte_ = ((r << 7) + kk * 64 + g * 16) ^ ((r & 7) << 4);
      short8 pa = *(const short8*)((const char*)myp + byte_);
#pragma unroll
      for (int n2 = 0; n2 < 2; ++n2) o[mt][n2] = MFMA16(pa, vb[kk][n2], o[mt][n2]);
    }
#pragma unroll
  for (int mt = 0; mt < 4; ++mt)
#pragma unroll
    for (int n2 = 0; n2 < 2; ++n2)
#pragma unroll
      for (int reg = 0; reg < 4; ++reg) {
        int r = mt * 16 + g * 4 + reg;
        if (r < 49) ao[(size_t)(win * 49 + r) * 128 + head * 32 + n2 * 16 + l15] = f2bf(o[mt][n2][reg]);
      }
}

// ---------------- K4: proj GEMM + bias + residual + LN2, no-LDS ----------------
__global__ __launch_bounds__(256) void k4_proj(const u16* __restrict__ ao, const u16* __restrict__ wot,
                                               const float* __restrict__ bo, const float* __restrict__ x,
                                               const float* __restrict__ g2, const float* __restrict__ b2,
                                               float* __restrict__ dout, u16* __restrict__ ln2) {
  int tid = threadIdx.x, lane = tid & 63, w = tid >> 6;
  int g = lane >> 4, l15 = lane & 15;
  int row0 = blockIdx.x * 256 + w * 64;
  short8 a[4][4];
#pragma unroll
  for (int mt = 0; mt < 4; ++mt)
#pragma unroll
    for (int kt = 0; kt < 4; ++kt)
      a[mt][kt] = *(const short8*)(ao + (size_t)(row0 + mt * 16 + l15) * 128 + kt * 32 + g * 8);
  const f32x4 vz = {0.f, 0.f, 0.f, 0.f};
  f32x4 acc[4][8];
#pragma unroll
  for (int i = 0; i < 4; ++i)
#pragma unroll
    for (int j = 0; j < 8; ++j) acc[i][j] = vz;
#pragma unroll
  for (int kt = 0; kt < 4; ++kt) {
    short8 bfr[8];
#pragma unroll
    for (int nt = 0; nt < 8; ++nt)
      bfr[nt] = *(const short8*)(wot + (size_t)(nt * 16 + l15) * 128 + kt * 32 + g * 8);
#pragma unroll
    for (int mt = 0; mt < 4; ++mt)
#pragma unroll
      for (int nt = 0; nt < 8; ++nt) acc[mt][nt] = MFMA16(a[mt][kt], bfr[nt], acc[mt][nt]);
  }
#pragma unroll
  for (int mt = 0; mt < 4; ++mt)
#pragma unroll
    for (int reg = 0; reg < 4; ++reg) {
      int token = row0 + mt * 16 + g * 4 + reg;
      float hv[8];
      float s1 = 0.f, s2 = 0.f;
#pragma unroll
      for (int nt = 0; nt < 8; ++nt) {
        int c = nt * 16 + l15;
        float v = acc[mt][nt][reg] + bo[c] + x[(size_t)token * 128 + c];
        dout[(size_t)token * 128 + c] = v;
        hv[nt] = v; s1 += v; s2 += v * v;
      }
#pragma unroll
      for (int o = 1; o < 16; o <<= 1) { s1 += __shfl_xor(s1, o); s2 += __shfl_xor(s2, o); }
      float mu = s1 * 0.0078125f;
      float rstd = rsqrtf(fmaxf(s2 * 0.0078125f - mu * mu, 0.f) + 1e-5f);
#pragma unroll
      for (int nt = 0; nt < 8; ++nt) {
        int c = nt * 16 + l15;
        ln2[(size_t)token * 128 + c] = f2bf((hv[nt] - mu) * rstd * g2[c] + b2[c]);
      }
    }
}

// ---------------- K5: MLP GEMM1 + gelu, no-LDS (M=200704, K=128, N=512) ----------------
__global__ __launch_bounds__(256) void k5_mlp1(const u16* __restrict__ ln2, const u16* __restrict__ w1t,
                                               const float* __restrict__ b1, u16* __restrict__ g1) {
  int tid = threadIdx.x, lane = tid & 63, w = tid >> 6;
  int g = lane >> 4, l15 = lane & 15;
  int row0 = blockIdx.x * 256 + w * 64;
  short8 a[4][4];
#pragma unroll
  for (int mt = 0; mt < 4; ++mt)
#pragma unroll
    for (int kt = 0; kt < 4; ++kt)
      a[mt][kt] = *(const short8*)(ln2 + (size_t)(row0 + mt * 16 + l15) * 128 + kt * 32 + g * 8);
  const f32x4 vz = {0.f, 0.f, 0.f, 0.f};
  for (int nb = 0; nb < 8; ++nb) {
    f32x4 acc[4][4];
#pragma unroll
    for (int i = 0; i < 4; ++i)
#pragma unroll
      for (int j = 0; j < 4; ++j) acc[i][j] = vz;
#pragma unroll
    for (int kt = 0; kt < 4; ++kt) {
      short8 bfr[4];
#pragma unroll
      for (int nt = 0; nt < 4; ++nt)
        bfr[nt] = *(const short8*)(w1t + (size_t)(nb * 64 + nt * 16 + l15) * 128 + kt * 32 + g * 8);
#pragma unroll
      for (int mt = 0; mt < 4; ++mt)
#pragma unroll
        for (int nt = 0; nt < 4; ++nt) acc[mt][nt] = MFMA16(a[mt][kt], bfr[nt], acc[mt][nt]);
    }
#pragma unroll
    for (int mt = 0; mt < 4; ++mt)
#pragma unroll
      for (int nt = 0; nt < 4; ++nt) {
        int ng = nb * 64 + nt * 16 + l15;
        float bias = b1[ng];
#pragma unroll
        for (int reg = 0; reg < 4; ++reg) {
          int token = row0 + mt * 16 + g * 4 + reg;
          g1[(size_t)token * 512 + ng] = f2bf(gelu_f(acc[mt][nt][reg] + bias));
        }
      }
  }
}

// ---------------- K6: MLP GEMM2 + bias + residual, no-LDS (K=512, N=128) ----------------
__global__ __launch_bounds__(256) void k6_mlp2(const u16* __restrict__ g1, const u16* __restrict__ w2t,
                                               const float* __restrict__ b2, float* __restrict__ dout) {
  int tid = threadIdx.x, lane = tid & 63, w = tid >> 6;
  int g = lane >> 4, l15 = lane & 15;
  int row0 = blockIdx.x * 256 + w * 64;
  const f32x4 vz = {0.f, 0.f, 0.f, 0.f};
  f32x4 acc[4][8];
#pragma unroll
  for (int i = 0; i < 4; ++i)
#pragma unroll
    for (int j = 0; j < 8; ++j) acc[i][j] = vz;
#pragma unroll
  for (int kt = 0; kt < 16; ++kt) {
    short8 a[4];
#pragma unroll
    for (int mt = 0; mt < 4; ++mt)
      a[mt] = *(const short8*)(g1 + (size_t)(row0 + mt * 16 + l15) * 512 + kt * 32 + g * 8);
    short8 bfr[8];
#pragma unroll
    for (int nt = 0; nt < 8; ++nt)
      bfr[nt] = *(const short8*)(w2t + (size_t)(nt * 16 + l15) * 512 + kt * 32 + g * 8);
#pragma unroll
    for (int mt = 0; mt < 4; ++mt)
#pragma unroll
      for (int nt = 0; nt < 8; ++nt) acc[mt][nt] = MFMA16(a[mt], bfr[nt], acc[mt][nt]);
  }
#pragma unroll
  for (int mt = 0; mt < 4; ++mt)
#pragma unroll
    for (int nt = 0; nt < 8; ++nt) {
      int c = nt * 16 + l15;
      float bias = b2[c];
#pragma unroll
      for (int reg = 0; reg < 4; ++reg) {
        int token = row0 + mt * 16 + g * 4 + reg;
        size_t i = (size_t)token * 128 + c;
        dout[i] = acc[mt][nt][reg] + bias + dout[i];
      }
    }
}

extern "C" void kernel_launch(void* const* d_in, const int* in_sizes, int n_in,
                              void* d_out, int out_size, void* d_ws, size_t ws_size,
                              hipStream_t stream) {
  const float* x    = (const float*)d_in[0];
  const float* wq   = (const float*)d_in[1];
  const float* bq   = (const float*)d_in[2];
  const float* wk   = (const float*)d_in[3];
  const float* bk   = (const float*)d_in[4];
  const float* wv   = (const float*)d_in[5];
  const float* bv   = (const float*)d_in[6];
  const float* wo   = (const float*)d_in[7];
  const float* bo   = (const float*)d_in[8];
  const float* rel  = (const float*)d_in[9];
  const float* ln1g = (const float*)d_in[10];
  const float* ln1b = (const float*)d_in[11];
  const float* ln2g = (const float*)d_in[12];
  const float* ln2b = (const float*)d_in[13];
  const float* w1   = (const float*)d_in[14];
  const float* b1   = (const float*)d_in[15];
  const float* w2   = (const float*)d_in[16];
  const float* b2   = (const float*)d_in[17];
  float* out = (float*)d_out;
  char* ws = (char*)d_ws;

  const size_t TOK = 200704;
  float* bmask = (float*)(ws);                                   // 4 MB
  u16* wqkvt = (u16*)(ws + (size_t)(4 << 20));                   // 192 KB
  u16* wot   = (u16*)(ws + (size_t)(4 << 20) + 196608);          // 32 KB
  u16* w1t   = (u16*)(ws + (size_t)(4 << 20) + 229376);          // 128 KB
  u16* w2t   = (u16*)(ws + (size_t)(4 << 20) + 360448);          // 128 KB
  float* bqkv = (float*)(ws + (size_t)(4 << 20) + 491520);       // 1.5 KB
  const size_t SB = TOK * 128 * 2;
  u16* hwin = (u16*)(ws + (size_t)(8 << 20));
  u16* qb   = (u16*)(ws + (size_t)(8 << 20) + SB);
  u16* kb   = (u16*)(ws + (size_t)(8 << 20) + 2 * SB);
  u16* vt   = (u16*)(ws + (size_t)(8 << 20) + 3 * SB);           // 64 MB
  u16* attn = hwin;
  u16* ln2  = qb;
  u16* g1b  = kb;

  k0_weights<<<770, 256, 0, stream>>>(wq, wk, wv, wo, w1, w2, bq, bk, bv,
                                      wqkvt, wot, w1t, w2t, bqkv);
  k0_biasmask<<<4096, 256, 0, stream>>>(rel, bmask);
  k1_ln1<<<50176, 256, 0, stream>>>(x, ln1g, ln1b, hwin);
  k2_qkv<<<784, 256, 0, stream>>>(hwin, wqkvt, bqkv, qb, kb, vt);
  k3_attn<<<4096, 256, 0, stream>>>(qb, kb, vt, bmask, attn);
  k4_proj<<<784, 256, 0, stream>>>(attn, wot, bo, x, ln2g, ln2b, out, ln2);
  k5_mlp1<<<784, 256, 0, stream>>>(ln2, w1t, b1, g1b);
  k6_mlp2<<<784, 256, 0, stream>>>(g1b, w2t, b2, out);
}

// Round 3
// 884.256 us; speedup vs baseline: 1.0091x; 1.0091x over previous
//
#include <hip/hip_runtime.h>

typedef __attribute__((ext_vector_type(8))) short short8;
typedef __attribute__((ext_vector_type(4))) float f32x4;
typedef unsigned short u16;
typedef unsigned int u32;

#define MFMA16(a, b, c) __builtin_amdgcn_mfma_f32_16x16x32_bf16((a), (b), (c), 0, 0, 0)
#define SCALE_Q 0.1767766952966369f
#define TOKENS 200704

__device__ __forceinline__ u16 f2bf(float x) {
  u32 u = __float_as_uint(x);
  u32 r = u + 0x7FFF + ((u >> 16) & 1);
  return (u16)(r >> 16);
}

__device__ __forceinline__ float gelu_f(float x) {
  float u = 0.7978845608f * (x + 0.044715f * x * x * x);
  float e = __expf(2.f * u);
  float t = 1.f - 2.f / (e + 1.f);
  return 0.5f * x * (1.f + t);
}

// pack (me, lane^1's me) into u32 on even lanes
__device__ __forceinline__ u32 pairpack(u16 me, int lane) {
  u32 pv = (u32)__shfl_xor((int)me, 1);
  return (u32)me | (pv << 16);
}

// ---------------- K0a: weight transpose + bf16 cast ----------------
__global__ __launch_bounds__(256) void k0_weights(
    const float* __restrict__ wq, const float* __restrict__ wk, const float* __restrict__ wv,
    const float* __restrict__ wo, const float* __restrict__ w1, const float* __restrict__ w2,
    const float* __restrict__ bq, const float* __restrict__ bk, const float* __restrict__ bv,
    u16* __restrict__ wqkvt, u16* __restrict__ wot, u16* __restrict__ w1t, u16* __restrict__ w2t,
    float* __restrict__ bqkv) {
  int idx = blockIdx.x * 256 + threadIdx.x;
  if (idx < 49152) {
    int n = idx >> 7, k = idx & 127;
    float v;
    if (n < 128) v = wq[k * 128 + n] * SCALE_Q;
    else if (n < 256) v = wk[k * 128 + (n - 128)];
    else v = wv[k * 128 + (n - 256)];
    wqkvt[idx] = f2bf(v);
  } else if (idx < 65536) {
    int j = idx - 49152;
    int n = j >> 7, k = j & 127;
    wot[j] = f2bf(wo[k * 128 + n]);
  } else if (idx < 131072) {
    int j = idx - 65536;
    int n = j >> 7, k = j & 127;
    w1t[j] = f2bf(w1[k * 512 + n]);
  } else if (idx < 196608) {
    int j = idx - 131072;
    int n = j >> 9, k = j & 511;
    w2t[j] = f2bf(w2[k * 128 + n]);
  } else if (idx < 196992) {
    int n = idx - 196608;
    float v;
    if (n < 128) v = bq[n] * SCALE_Q;
    else if (n < 256) v = bk[n - 128];
    else v = bv[n - 256];
    bqkv[n] = v;
  }
}

// ---------------- K0b: bias+mask table in MFMA C-fragment layout ----------------
__global__ __launch_bounds__(256) void k0_biasmask(const float* __restrict__ rel, float* __restrict__ bm) {
  int idx = blockIdx.x * 256 + threadIdx.x;
  int reg = idx & 3;
  int lane = (idx >> 2) & 63;
  int nt = (idx >> 8) & 3;
  int mt = (idx >> 10) & 3;
  int h = (idx >> 12) & 3;
  int wi = idx >> 14;
  int r = mt * 16 + ((lane >> 4) << 2) + reg;
  int c = nt * 16 + (lane & 15);
  float v = -1e30f;
  if (r < 49 && c < 49) {
    int qr = r / 7, qc = r % 7, kr = c / 7, kc = c % 7;
    int i0 = (kr - qr + 13) % 13, i1 = (kc - qc + 13) % 13;
    v = rel[(i0 * 13 + i1) * 4 + h];
    int gh = (wi >> 3) * 7 + qr, gw = (wi & 7) * 7 + qc;
    int kh = (wi >> 3) * 7 + kr, kw = (wi & 7) * 7 + kc;
    int rq = (gh < 49 ? 0 : (gh < 53 ? 1 : 2)) * 3 + (gw < 49 ? 0 : (gw < 53 ? 1 : 2));
    int rk = (kh < 49 ? 0 : (kh < 53 ? 1 : 2)) * 3 + (kw < 49 ? 0 : (kw < 53 ? 1 : 2));
    if (rq != rk) v -= 100.f;
  }
  bm[idx] = v;
}

// ---------------- K1: LN1 + roll + window partition -> bf16 ----------------
__global__ __launch_bounds__(256) void k1_ln1(const float* __restrict__ x, const float* __restrict__ g,
                                              const float* __restrict__ b, u16* __restrict__ hwin) {
  int wid = threadIdx.x >> 6, lane = threadIdx.x & 63;
  int t = blockIdx.x * 4 + wid;
  float2 v = *(const float2*)(x + (size_t)t * 128 + lane * 2);
  float s = v.x + v.y;
#pragma unroll
  for (int o = 1; o < 64; o <<= 1) s += __shfl_xor(s, o);
  float mu = s * 0.0078125f;
  float dx = v.x - mu, dy = v.y - mu;
  float q = dx * dx + dy * dy;
#pragma unroll
  for (int o = 1; o < 64; o <<= 1) q += __shfl_xor(q, o);
  float rstd = rsqrtf(q * 0.0078125f + 1e-5f);
  float y0 = dx * rstd * g[lane * 2] + b[lane * 2];
  float y1 = dy * rstd * g[lane * 2 + 1] + b[lane * 2 + 1];
  int bi = t / 3136, hw = t - bi * 3136;
  int oh = hw / 56, ow = hw - oh * 56;
  int gh = oh - 3; if (gh < 0) gh += 56;
  int gw = ow - 3; if (gw < 0) gw += 56;
  int win = bi * 64 + (gh / 7) * 8 + gw / 7;
  int n = (gh % 7) * 7 + (gw % 7);
  u32 packed = (u32)f2bf(y0) | ((u32)f2bf(y1) << 16);
  *(u32*)(hwin + (size_t)(win * 49 + n) * 128 + lane * 2) = packed;
}

// ---------------- K2: QKV GEMM, 32-row waves, coalesced packed stores ----------------
__global__ __launch_bounds__(256) void k2_qkv(const u16* __restrict__ hwin, const u16* __restrict__ wt,
                                              const float* __restrict__ bqkv, u16* __restrict__ qb,
                                              u16* __restrict__ kb, u16* __restrict__ vb) {
  int tid = threadIdx.x, lane = tid & 63, w = tid >> 6;
  int g = lane >> 4, l15 = lane & 15;
  int row0 = blockIdx.x * 128 + w * 32;
  short8 a[2][4];
#pragma unroll
  for (int mt = 0; mt < 2; ++mt)
#pragma unroll
    for (int kt = 0; kt < 4; ++kt)
      a[mt][kt] = *(const short8*)(hwin + (size_t)(row0 + mt * 16 + l15) * 128 + kt * 32 + g * 8);
  const f32x4 vz = {0.f, 0.f, 0.f, 0.f};
  for (int nb = 0; nb < 6; ++nb) {
    f32x4 acc[2][4];
#pragma unroll
    for (int i = 0; i < 2; ++i)
#pragma unroll
      for (int j = 0; j < 4; ++j) acc[i][j] = vz;
#pragma unroll
    for (int kt = 0; kt < 4; ++kt) {
      short8 bfr[4];
#pragma unroll
      for (int nt = 0; nt < 4; ++nt)
        bfr[nt] = *(const short8*)(wt + (size_t)(nb * 64 + nt * 16 + l15) * 128 + kt * 32 + g * 8);
#pragma unroll
      for (int mt = 0; mt < 2; ++mt)
#pragma unroll
        for (int nt = 0; nt < 4; ++nt) acc[mt][nt] = MFMA16(a[mt][kt], bfr[nt], acc[mt][nt]);
    }
    u16* dst; int cb;
    if (nb < 2) { dst = qb; cb = nb * 64; }
    else if (nb < 4) { dst = kb; cb = (nb - 2) * 64; }
    else { dst = vb; cb = (nb - 4) * 64; }
#pragma unroll
    for (int mt = 0; mt < 2; ++mt)
#pragma unroll
      for (int nt = 0; nt < 4; ++nt) {
        int c = cb + nt * 16 + l15;
        float bias = bqkv[nb * 64 + nt * 16 + l15];
#pragma unroll
        for (int reg = 0; reg < 4; ++reg) {
          int token = row0 + mt * 16 + g * 4 + reg;
          u16 me = f2bf(acc[mt][nt][reg] + bias);
          u32 word = pairpack(me, lane);
          if (!(lane & 1)) *(u32*)(dst + (size_t)token * 128 + c) = word;
        }
      }
  }
}

// ---------------- K3: attention + proj + residual + LN2, one block per window ----------------
__global__ __launch_bounds__(256) void k3_attn(const u16* __restrict__ qb, const u16* __restrict__ kb,
                                               const u16* __restrict__ vb, const float* __restrict__ bm,
                                               const u16* __restrict__ wot, const float* __restrict__ bo,
                                               const float* __restrict__ x, const float* __restrict__ g2,
                                               const float* __restrict__ b2, float* __restrict__ dout,
                                               u16* __restrict__ ln2) {
  __shared__ u16 smem[16384 + 8192];       // pl: 4x8KB P-tiles; vt: 16KB V^T; ao aliases pl
  u16* pl = smem;
  u16* vtl = smem + 16384;
  u16* aol = smem;
  int win = blockIdx.x;
  int tid = threadIdx.x;
  int lane = tid & 63, head = tid >> 6;
  int g = lane >> 4, l15 = lane & 15;

  // ---- stage V -> LDS transposed [128 dims][64 tokens], swizzled ----
  {
    int t = tid >> 2, dq = tid & 3;
    long grow = (long)win * 49 + t;
    bool valid = (t < 49) && (grow < TOKENS);
    short8 r[4];
#pragma unroll
    for (int c = 0; c < 4; ++c) {
      if (valid) r[c] = *(const short8*)(vb + grow * 128 + dq * 32 + c * 8);
      else r[c] = short8{0, 0, 0, 0, 0, 0, 0, 0};
    }
#pragma unroll
    for (int c = 0; c < 4; ++c)
#pragma unroll
      for (int e = 0; e < 8; ++e) {
        int d = dq * 32 + c * 8 + e;
        int byte_ = (d * 128 + t * 2) ^ ((((d & 7) ^ ((d >> 3) & 7))) << 4);
        *(u16*)((char*)vtl + byte_) = (u16)r[c][e];
      }
  }

  u16* myp = pl + head * 4096;
  short8 aq[4], bk_[4];
#pragma unroll
  for (int mt = 0; mt < 4; ++mt)
    aq[mt] = *(const short8*)(qb + (size_t)(win * 49 + mt * 16 + l15) * 128 + head * 32 + g * 8);
#pragma unroll
  for (int nt = 0; nt < 4; ++nt)
    bk_[nt] = *(const short8*)(kb + (size_t)(win * 49 + nt * 16 + l15) * 128 + head * 32 + g * 8);
  const f32x4* bmv = (const f32x4*)bm + ((win & 63) * 4 + head) * 1024;
  f32x4 s[4][4];
#pragma unroll
  for (int mt = 0; mt < 4; ++mt)
#pragma unroll
    for (int nt = 0; nt < 4; ++nt) s[mt][nt] = bmv[(mt * 4 + nt) * 64 + lane];
#pragma unroll
  for (int mt = 0; mt < 4; ++mt)
#pragma unroll
    for (int nt = 0; nt < 4; ++nt) s[mt][nt] = MFMA16(aq[mt], bk_[nt], s[mt][nt]);
#pragma unroll
  for (int mt = 0; mt < 4; ++mt)
#pragma unroll
    for (int reg = 0; reg < 4; ++reg) {
      float m = fmaxf(fmaxf(s[mt][0][reg], s[mt][1][reg]), fmaxf(s[mt][2][reg], s[mt][3][reg]));
#pragma unroll
      for (int o = 1; o < 16; o <<= 1) m = fmaxf(m, __shfl_xor(m, o));
      float p0 = __expf(s[mt][0][reg] - m);
      float p1 = __expf(s[mt][1][reg] - m);
      float p2 = __expf(s[mt][2][reg] - m);
      float p3 = __expf(s[mt][3][reg] - m);
      float sum = p0 + p1 + p2 + p3;
#pragma unroll
      for (int o = 1; o < 16; o <<= 1) sum += __shfl_xor(sum, o);
      float rinv = 1.f / sum;
      s[mt][0][reg] = p0 * rinv; s[mt][1][reg] = p1 * rinv;
      s[mt][2][reg] = p2 * rinv; s[mt][3][reg] = p3 * rinv;
    }
#pragma unroll
  for (int mt = 0; mt < 4; ++mt)
#pragma unroll
    for (int nt = 0; nt < 4; ++nt)
#pragma unroll
      for (int reg = 0; reg < 4; ++reg) {
        int r = mt * 16 + g * 4 + reg, c = nt * 16 + l15;
        int byte_ = ((r << 7) + (c << 1)) ^ ((r & 7) << 4);
        *(u16*)((char*)myp + byte_) = f2bf(s[mt][nt][reg]);
      }
  __syncthreads();   // P + V^T staged

  // ---- PV ----
  short8 vf[2][2];
#pragma unroll
  for (int kk = 0; kk < 2; ++kk)
#pragma unroll
    for (int n2 = 0; n2 < 2; ++n2) {
      int d = head * 32 + n2 * 16 + l15;
      int byte_ = (d * 128 + (kk * 32 + g * 8) * 2) ^ ((((d & 7) ^ ((d >> 3) & 7))) << 4);
      vf[kk][n2] = *(const short8*)((const char*)vtl + byte_);
    }
  const f32x4 vz = {0.f, 0.f, 0.f, 0.f};
  f32x4 o[4][2];
#pragma unroll
  for (int mt = 0; mt < 4; ++mt) { o[mt][0] = vz; o[mt][1] = vz; }
#pragma unroll
  for (int mt = 0; mt < 4; ++mt)
#pragma unroll
    for (int kk = 0; kk < 2; ++kk) {
      int r = mt * 16 + l15;
      int byte_ = ((r << 7) + kk * 64 + g * 16) ^ ((r & 7) << 4);
      short8 pa = *(const short8*)((const char*)myp + byte_);
#pragma unroll
      for (int n2 = 0; n2 < 2; ++n2) o[mt][n2] = MFMA16(pa, vf[kk][n2], o[mt][n2]);
    }
  __syncthreads();   // everyone done reading pl

  // ---- ao -> LDS (overlay pl), [64 rows][128 cols], swizzled, pair-packed ----
#pragma unroll
  for (int mt = 0; mt < 4; ++mt)
#pragma unroll
    for (int n2 = 0; n2 < 2; ++n2)
#pragma unroll
      for (int reg = 0; reg < 4; ++reg) {
        int r = mt * 16 + g * 4 + reg, c = head * 32 + n2 * 16 + l15;
        u16 me = f2bf(o[mt][n2][reg]);
        u32 word = pairpack(me, lane);
        if (!(lane & 1)) {
          int byte_ = ((r << 8) + c * 2) ^ ((r & 7) << 4);
          *(u32*)((char*)aol + byte_) = word;
        }
      }
  __syncthreads();

  // ---- proj: wave w -> rows w*16..w*16+15 ----
  int w = head;
  f32x4 pacc[8];
#pragma unroll
  for (int nt = 0; nt < 8; ++nt) pacc[nt] = vz;
#pragma unroll
  for (int kt = 0; kt < 4; ++kt) {
    int row = w * 16 + l15;
    int byte_ = ((row << 8) + kt * 64 + g * 16) ^ ((row & 7) << 4);
    short8 af = *(const short8*)((const char*)aol + byte_);
#pragma unroll
    for (int nt = 0; nt < 8; ++nt) {
      short8 bf = *(const short8*)(wot + (size_t)(nt * 16 + l15) * 128 + kt * 32 + g * 8);
      pacc[nt] = MFMA16(af, bf, pacc[nt]);
    }
  }
#pragma unroll
  for (int reg = 0; reg < 4; ++reg) {
    int row = w * 16 + g * 4 + reg;
    if (row < 49) {
      size_t token = (size_t)win * 49 + row;
      float hv[8];
      float s1 = 0.f, s2 = 0.f;
#pragma unroll
      for (int nt = 0; nt < 8; ++nt) {
        int c = nt * 16 + l15;
        float v = pacc[nt][reg] + bo[c] + x[token * 128 + c];
        dout[token * 128 + c] = v;
        hv[nt] = v; s1 += v; s2 += v * v;
      }
#pragma unroll
      for (int o = 1; o < 16; o <<= 1) { s1 += __shfl_xor(s1, o); s2 += __shfl_xor(s2, o); }
      float mu = s1 * 0.0078125f;
      float rstd = rsqrtf(fmaxf(s2 * 0.0078125f - mu * mu, 0.f) + 1e-5f);
#pragma unroll
      for (int nt = 0; nt < 8; ++nt) {
        int c = nt * 16 + l15;
        u16 me = f2bf((hv[nt] - mu) * rstd * g2[c] + b2[c]);
        u32 word = pairpack(me, lane);
        if (!(lane & 1)) *(u32*)(ln2 + token * 128 + c) = word;
      }
    }
  }
}

// ---------------- K5: fused MLP (64-token strip, h1 in 64KB LDS) ----------------
__global__ __launch_bounds__(256) void k5_mlp(const u16* __restrict__ ln2, const u16* __restrict__ w1t,
                                              const float* __restrict__ b1, const u16* __restrict__ w2t,
                                              const float* __restrict__ b2, float* __restrict__ dout) {
  __shared__ u16 h1[64 * 512];              // 64KB, row stride 1024B, XOR swizzle (r&7)<<4
  int tid = threadIdx.x, lane = tid & 63, w = tid >> 6;
  int g = lane >> 4, l15 = lane & 15;
  int row0 = blockIdx.x * 64;
  const f32x4 vz = {0.f, 0.f, 0.f, 0.f};

  // phase A: wave w -> rows w*16..+15, all 512 cols
  {
    int r0 = w * 16;
    short8 a[4];
#pragma unroll
    for (int kt = 0; kt < 4; ++kt)
      a[kt] = *(const short8*)(ln2 + (size_t)(row0 + r0 + l15) * 128 + kt * 32 + g * 8);
    for (int nb = 0; nb < 8; ++nb) {
      f32x4 acc[4];
#pragma unroll
      for (int j = 0; j < 4; ++j) acc[j] = vz;
#pragma unroll
      for (int kt = 0; kt < 4; ++kt) {
        short8 bf[4];
#pragma unroll
        for (int nt = 0; nt < 4; ++nt)
          bf[nt] = *(const short8*)(w1t + (size_t)(nb * 64 + nt * 16 + l15) * 128 + kt * 32 + g * 8);
#pragma unroll
        for (int nt = 0; nt < 4; ++nt) acc[nt] = MFMA16(a[kt], bf[nt], acc[nt]);
      }
#pragma unroll
      for (int nt = 0; nt < 4; ++nt) {
        float bias = b1[nb * 64 + nt * 16 + l15];
#pragma unroll
        for (int reg = 0; reg < 4; ++reg) {
          int r = r0 + g * 4 + reg;
          int c = nb * 64 + nt * 16 + l15;
          u16 me = f2bf(gelu_f(acc[nt][reg] + bias));
          u32 word = pairpack(me, lane);
          if (!(lane & 1)) {
            int byte_ = (r * 1024 + c * 2) ^ ((r & 7) << 4);
            *(u32*)((char*)h1 + byte_) = word;
          }
        }
      }
    }
  }
  __syncthreads();

  // phase B: wave w -> cols w*32..+31, rows all 64
  {
    int c0 = w * 32;
    f32x4 acc2[4][2];
#pragma unroll
    for (int i = 0; i < 4; ++i) { acc2[i][0] = vz; acc2[i][1] = vz; }
#pragma unroll
    for (int kt = 0; kt < 16; ++kt) {
      short8 bf[2];
#pragma unroll
      for (int n2 = 0; n2 < 2; ++n2)
        bf[n2] = *(const short8*)(w2t + (size_t)(c0 + n2 * 16 + l15) * 512 + kt * 32 + g * 8);
#pragma unroll
      for (int mt = 0; mt < 4; ++mt) {
        int r = mt * 16 + l15;
        int byte_ = (r * 1024 + kt * 64 + g * 16) ^ ((r & 7) << 4);
        short8 af = *(const short8*)((const char*)h1 + byte_);
#pragma unroll
        for (int n2 = 0; n2 < 2; ++n2) acc2[mt][n2] = MFMA16(af, bf[n2], acc2[mt][n2]);
      }
    }
#pragma unroll
    for (int mt = 0; mt < 4; ++mt)
#pragma unroll
      for (int n2 = 0; n2 < 2; ++n2) {
        int c = c0 + n2 * 16 + l15;
        float bias = b2[c];
#pragma unroll
        for (int reg = 0; reg < 4; ++reg) {
          size_t token = (size_t)row0 + mt * 16 + g * 4 + reg;
          size_t i = token * 128 + c;
          dout[i] = acc2[mt][n2][reg] + bias + dout[i];
        }
      }
  }
}

extern "C" void kernel_launch(void* const* d_in, const int* in_sizes, int n_in,
                              void* d_out, int out_size, void* d_ws, size_t ws_size,
                              hipStream_t stream) {
  const float* x    = (const float*)d_in[0];
  const float* wq   = (const float*)d_in[1];
  const float* bq   = (const float*)d_in[2];
  const float* wk   = (const float*)d_in[3];
  const float* bk   = (const float*)d_in[4];
  const float* wv   = (const float*)d_in[5];
  const float* bv   = (const float*)d_in[6];
  const float* wo   = (const float*)d_in[7];
  const float* bo   = (const float*)d_in[8];
  const float* rel  = (const float*)d_in[9];
  const float* ln1g = (const float*)d_in[10];
  const float* ln1b = (const float*)d_in[11];
  const float* ln2g = (const float*)d_in[12];
  const float* ln2b = (const float*)d_in[13];
  const float* w1   = (const float*)d_in[14];
  const float* b1   = (const float*)d_in[15];
  const float* w2   = (const float*)d_in[16];
  const float* b2   = (const float*)d_in[17];
  float* out = (float*)d_out;
  char* ws = (char*)d_ws;

  float* bmask = (float*)(ws);                                   // 4 MB
  u16* wqkvt = (u16*)(ws + (size_t)(4 << 20));
  u16* wot   = (u16*)(ws + (size_t)(4 << 20) + 196608);
  u16* w1t   = (u16*)(ws + (size_t)(4 << 20) + 229376);
  u16* w2t   = (u16*)(ws + (size_t)(4 << 20) + 360448);
  float* bqkv = (float*)(ws + (size_t)(4 << 20) + 491520);
  const size_t SB = (size_t)TOKENS * 128 * 2;
  u16* hwin = (u16*)(ws + (size_t)(8 << 20));
  u16* qb   = (u16*)(ws + (size_t)(8 << 20) + SB);
  u16* kb   = (u16*)(ws + (size_t)(8 << 20) + 2 * SB);
  u16* vb   = (u16*)(ws + (size_t)(8 << 20) + 3 * SB);
  u16* ln2  = hwin;   // hwin dead after k2

  k0_weights<<<770, 256, 0, stream>>>(wq, wk, wv, wo, w1, w2, bq, bk, bv,
                                      wqkvt, wot, w1t, w2t, bqkv);
  k0_biasmask<<<4096, 256, 0, stream>>>(rel, bmask);
  k1_ln1<<<50176, 256, 0, stream>>>(x, ln1g, ln1b, hwin);
  k2_qkv<<<1568, 256, 0, stream>>>(hwin, wqkvt, bqkv, qb, kb, vb);
  k3_attn<<<4096, 256, 0, stream>>>(qb, kb, vb, bmask, wot, bo, x, ln2g, ln2b, out, ln2);
  k5_mlp<<<3136, 256, 0, stream>>>(ln2, w1t, b1, w2t, b2, out);
}